// Round 8
// baseline (8996.614 us; speedup 1.0000x reference)
//
#include <hip/hip_runtime.h>
#include <stdint.h>

#define B_   64
#define N_   256
#define S_   2000
#define K_   100
#define BIL_ 4
#define NITER_ 200
#define JITTER_ 1e-4f
#define SAFETY_ 0.5f
#define PART_ 4
#define SCH_  (S_ / PART_)   // 500 scenarios per block

// ---- ws layout (offsets in float units) ----
#define OFF_LC16  ((size_t)0)                                   // bf16 L col-major
#define OFF_LR16  (OFF_LC16 + (size_t)B_ * N_ * N_ / 2)         // bf16 L row-major
#define OFF_EPST  (OFF_LR16 + (size_t)B_ * N_ * N_ / 2)         // bf16 epsT[b][n][s]
#define OFF_EPSRM (OFF_EPST + (size_t)B_ * N_ * S_ / 2)         // bf16 eps[b][s][n] (& temp fp32 Lc)
#define OFF_LOSS  (OFF_EPSRM + (size_t)B_ * S_ * N_ / 2)        // uint loss keys, double-buffered
#define OFF_BAR   (OFF_LOSS + (size_t)2 * B_ * S_)              // int barrier counters

// ---------------- helpers ----------------
__device__ __forceinline__ float wred_f(float x) {
#pragma unroll
  for (int off = 32; off > 0; off >>= 1) x += __shfl_xor(x, off);
  return x;
}
// monotone key: larger loss -> SMALLER key (top-K largest = K smallest keys)
__device__ __forceinline__ unsigned keyd(float x) {
  unsigned u = __float_as_uint(x);
  unsigned ku = (u & 0x80000000u) ? ~u : (u | 0x80000000u);
  return ~ku;
}
__device__ __forceinline__ uint16_t f2b(float f) {  // RNE fp32->bf16
  uint32_t u = __float_as_uint(f);
  uint32_t r = u + 0x7FFFu + ((u >> 16) & 1u);
  return (uint16_t)(r >> 16);
}
__device__ __forceinline__ float blo(uint32_t u) { return __uint_as_float(u << 16); }
__device__ __forceinline__ float bhi(uint32_t u) { return __uint_as_float(u & 0xFFFF0000u); }

// Fixed-point simplex projection (same map as reference's sort formula; unique
// KKT fixed point). Warm-started from theta0; active count via ballots (SALU).
__device__ __forceinline__ float michelot4(const float vp[4], float z, float theta0) {
  float theta = theta0;
  int prev = -1;
  for (int pass = 0; pass < 300; ++pass) {
    const bool a0 = vp[0] > theta, a1 = vp[1] > theta, a2 = vp[2] > theta, a3 = vp[3] > theta;
    float ls = 0.0f;
    if (a0) ls += vp[0];
    if (a1) ls += vp[1];
    if (a2) ls += vp[2];
    if (a3) ls += vp[3];
    const int lc = __popcll(__ballot(a0)) + __popcll(__ballot(a1)) +
                   __popcll(__ballot(a2)) + __popcll(__ballot(a3));
    ls = wred_f(ls);
    if (lc == 0) {  // over-warm start excluded everything: cold restart
      theta = -1e30f;
      prev = -1;
      continue;
    }
    const float nt = (ls - z) / (float)lc;
    theta = nt;
    if (lc == prev) break;
    prev = lc;
  }
  return theta;
}

__device__ __forceinline__ void proj_store(const float y[4], float fl_bil, float mass, float muf,
                                           const float* __restrict__ muB, int ln, float theta0,
                                           float* w_s, float* c_sh, float* th_sh) {
  float vp[4];
#pragma unroll
  for (int j = 0; j < 4; ++j) {
    const int n = 4 * ln + j;
    vp[j] = y[j] - ((n == BIL_) ? fl_bil : 0.0f);
  }
  const float theta = michelot4(vp, mass, theta0);
  const float4 m4 = *(const float4*)(muB + 4 * ln);
  const float mm[4] = {m4.x, m4.y, m4.z, m4.w};
  float wj[4];
  float cp = 0.0f;
#pragma unroll
  for (int j = 0; j < 4; ++j) {
    const int n = 4 * ln + j;
    wj[j] = fmaxf(vp[j] - theta, 0.0f) + ((n == BIL_) ? fl_bil : 0.0f);
    cp = fmaf(muf * mm[j], wj[j], cp);
  }
  cp = wred_f(cp);
  if (ln == 0) {
    *c_sh = cp;
    *th_sh = theta;
  }
  *(float4*)(w_s + 4 * ln) = make_float4(wj[0], wj[1], wj[2], wj[3]);
}

// ---------------- Cholesky v3: one block (512 thr) per batch (proven r3) ----------------
__global__ __launch_bounds__(512) void chol_kernel(const float* __restrict__ sigma,
                                                   float* __restrict__ Lc) {
  const int b = blockIdx.x;
  const int tid = threadIdx.x;
  const int i = tid & 255;
  const int half = tid >> 8;
  const float* Sg = sigma + (size_t)b * N_ * N_;
  float* L = Lc + (size_t)b * N_ * N_;
  __shared__ __align__(16) float slab[248 * 8];
  __shared__ __align__(16) float spart[256][8];
  __shared__ __align__(16) float pnl[64];

  for (int j0 = 0; j0 < N_; j0 += 8) {
    for (int x = tid; x < j0 * 8; x += 512) {
      const int k = x >> 3, jj = x & 7;
      slab[x] = L[(size_t)k * N_ + (j0 + jj)];
    }
    float s[8];
    if (half == 0) {
#pragma unroll
      for (int jj = 0; jj < 8; ++jj) {
        float a = Sg[(size_t)(j0 + jj) * N_ + i];
        if (i == j0 + jj) a += JITTER_;
        s[jj] = a;
      }
    } else {
#pragma unroll
      for (int jj = 0; jj < 8; ++jj) s[jj] = 0.0f;
    }
    __syncthreads();

    const int kb = half ? (j0 >> 1) : 0;
    const int ke = half ? j0 : (j0 >> 1);
#pragma unroll 4
    for (int k = kb; k < ke; ++k) {
      const float lk = L[(size_t)k * N_ + i];
      const float4 h0 = *(const float4*)&slab[k * 8];
      const float4 h1 = *(const float4*)&slab[k * 8 + 4];
      s[0] = fmaf(-lk, h0.x, s[0]);
      s[1] = fmaf(-lk, h0.y, s[1]);
      s[2] = fmaf(-lk, h0.z, s[2]);
      s[3] = fmaf(-lk, h0.w, s[3]);
      s[4] = fmaf(-lk, h1.x, s[4]);
      s[5] = fmaf(-lk, h1.y, s[5]);
      s[6] = fmaf(-lk, h1.z, s[6]);
      s[7] = fmaf(-lk, h1.w, s[7]);
    }
    if (half == 1) {
      *(float4*)&spart[i][0] = make_float4(s[0], s[1], s[2], s[3]);
      *(float4*)&spart[i][4] = make_float4(s[4], s[5], s[6], s[7]);
    }
    __syncthreads();

    if (half == 0) {
      const float4 p0 = *(const float4*)&spart[i][0];
      const float4 p1 = *(const float4*)&spart[i][4];
      s[0] += p0.x; s[1] += p0.y; s[2] += p0.z; s[3] += p0.w;
      s[4] += p1.x; s[5] += p1.y; s[6] += p1.z; s[7] += p1.w;
      if ((i >> 3) == (j0 >> 3)) {
        const int base = j0 & 63;
        const int r = i & 7;
        float l[8], di[8];
#pragma unroll
        for (int m = 0; m < 8; ++m) {
          const float smv = __shfl(s[m], base + m);
          const float d = sqrtf(smv);
          const float dinv = 1.0f / d;
          di[m] = dinv;
          float lm;
          if (r == m) lm = d;
          else if (r > m) lm = s[m] * dinv;
          else lm = 0.0f;
          l[m] = lm;
#pragma unroll
          for (int mm = m + 1; mm < 8; ++mm) {
            s[mm] = fmaf(-lm, __shfl(lm, base + mm), s[mm]);
          }
        }
#pragma unroll
        for (int m = 0; m < 8; ++m) pnl[r * 8 + m] = (m < r) ? l[m] : ((m == r) ? di[r] : 0.0f);
#pragma unroll
        for (int m = 0; m < 8; ++m) L[(size_t)(j0 + m) * N_ + i] = l[m];
      }
    }
    __syncthreads();

    if (half == 0 && (i >> 3) != (j0 >> 3)) {
      float l[8];
      if (i > j0) {
#pragma unroll
        for (int m = 0; m < 8; ++m) {
          float sm = s[m];
#pragma unroll
          for (int mm = 0; mm < 8; ++mm) {
            if (mm < m) sm = fmaf(-l[mm], pnl[m * 8 + mm], sm);
          }
          l[m] = sm * pnl[m * 8 + m];
        }
      } else {
#pragma unroll
        for (int m = 0; m < 8; ++m) l[m] = 0.0f;
      }
#pragma unroll
      for (int m = 0; m < 8; ++m) L[(size_t)(j0 + m) * N_ + i] = l[m];
    }
    __syncthreads();
  }
}

// ---------------- pack L ----------------
__global__ __launch_bounds__(256) void lpack_kernel(const float* __restrict__ Lc,
                                                    uint16_t* __restrict__ Lc16,
                                                    uint16_t* __restrict__ Lr16) {
  const int b = blockIdx.x;
  const float* Lp = Lc + (size_t)b * N_ * N_;
  uint16_t* C16 = Lc16 + (size_t)b * N_ * N_;
  uint16_t* R16 = Lr16 + (size_t)b * N_ * N_;
  __shared__ float tl[32][33];
  const int tx = threadIdx.x & 31;
  const int ty = threadIdx.x >> 5;
  for (int kt = 0; kt < 8; ++kt) {
    for (int it = 0; it < 8; ++it) {
#pragma unroll
      for (int rr = 0; rr < 4; ++rr) {
        const int k = kt * 32 + ty + 8 * rr;
        const int ii = it * 32 + tx;
        const float v = Lp[(size_t)k * N_ + ii];
        tl[ty + 8 * rr][tx] = v;
        C16[(size_t)k * N_ + ii] = f2b(v);
      }
      __syncthreads();
#pragma unroll
      for (int rr = 0; rr < 4; ++rr) {
        const int ii = it * 32 + ty + 8 * rr;
        const int k = kt * 32 + tx;
        R16[(size_t)ii * N_ + k] = f2b(tl[tx][ty + 8 * rr]);
      }
      __syncthreads();
    }
  }
}

// ---------------- eps -> bf16 both layouts; zero bar ----------------
__global__ __launch_bounds__(256) void etrans_kernel(const float* __restrict__ eps,
                                                     uint16_t* __restrict__ epsT16,
                                                     uint16_t* __restrict__ epsrm16,
                                                     int* __restrict__ bar) {
  const int b = blockIdx.x;
  const int s0 = blockIdx.y * 50;
  const int t = threadIdx.x;
  if (blockIdx.x == 0 && blockIdx.y == 0 && t < 64) bar[t] = 0;
  __shared__ float tl[50][257];
  const float* E = eps + ((size_t)b * S_ + s0) * N_;
  for (int p = 0; p < 50; ++p) tl[p][t] = E[(size_t)p * N_ + t];
  __syncthreads();
  uint16_t* RM = epsrm16 + ((size_t)b * S_ + s0) * N_;
  for (int p = 0; p < 50; ++p) RM[(size_t)p * N_ + t] = f2b(tl[p][t]);
  uint16_t* ET = epsT16 + (size_t)b * N_ * S_;
  const int g = t / 50, ss = t % 50;
  if (g < 5) {
    for (int q = 0; q < 52; ++q) {
      const int n = q * 5 + g;
      if (n < N_) ET[(size_t)n * S_ + s0 + ss] = f2b(tl[ss][n]);
    }
  }
}

// ---------------- solver: 4 blocks (1024 thr) per batch, grid 256, plain launch ----------------
// r8: wave-cooperative matvecs (no partial/reduce barrier pairs), inline e-reduce,
// warm-started ballot-based Michelot, pre-spin own-key histogram. 12 barriers/iter.
__global__ __launch_bounds__(1024) void solve_kernel(
    const float* __restrict__ mu, const int* __restrict__ pcrisis,
    const int* __restrict__ plam, const uint16_t* __restrict__ Lc16,
    const uint16_t* __restrict__ Lr16, const uint16_t* __restrict__ epsT16,
    const uint16_t* __restrict__ epsrm16, unsigned* __restrict__ lossbits,
    int* __restrict__ bar, float* __restrict__ out) {
  const int bx = blockIdx.x;
  const int b = bx & (B_ - 1);
  const int part = bx >> 6;  // 0..3; blocks b+64k land on XCD b%8 under %8 RR
  const int t = threadIdx.x;
  const int ln = t & 63;
  const int wv = t >> 6;
  const int s0 = part * SCH_;

  __shared__ __align__(16) float w_s[N_];
  __shared__ __align__(16) float v_s[N_];
  __shared__ __align__(16) float u_s[N_];
  __shared__ __align__(16) float scratch[8][N_];  // stage-1 partials AND e partials
  __shared__ __align__(16) uint16_t lists[S_];
  __shared__ __align__(16) int hist[4][256];      // one bank per radix pass
  __shared__ float c_sh;
  __shared__ float th_sh;
  __shared__ int lcnt;
  __shared__ float sum_sh;

  const int crisis = pcrisis[0];
  const int lamv = plam[0];
  const float muf = 1.0f + ((lamv > 0) ? (1.0f / fmaxf((float)lamv, 0.1f)) : 0.0f);
  const float fl_bil = SAFETY_ * (float)crisis;
  const float mass = 1.0f - fl_bil;

  const uint16_t* LcB = Lc16 + (size_t)b * N_ * N_;
  const uint16_t* LrB = Lr16 + (size_t)b * N_ * N_;
  const float* muB = mu + (size_t)b * N_;
  const uint16_t* epsTB = epsT16 + (size_t)b * N_ * S_;
  const uint16_t* epsRB = epsrm16 + (size_t)b * S_ * N_;
  float* sc1 = &scratch[0][0];

  // ---- w0 = proj(uniform), cold-start theta ----
  if (t < 64) {
    float y[4];
#pragma unroll
    for (int j = 0; j < 4; ++j) y[j] = 1.0f / (float)N_;
    proj_store(y, fl_bil, mass, muf, muB, ln, -1e30f, w_s, &c_sh, &th_sh);
  }
  __syncthreads();  // B0

  for (int it = 0; it < NITER_; ++it) {
    // ---- Phase V: v = L^T w wave-cooperative (wave wv owns k in [16wv,16wv+16));
    //      also zero hist banks + lcnt ----
    {
      ((int*)hist)[t] = 0;  // 4*256 == 1024 == blockDim
      if (t == 0) lcnt = 0;
      const float4 w4 = *(const float4*)(w_s + 4 * ln);
      float vk = 0.0f;
#pragma unroll
      for (int j = 0; j < 16; ++j) {
        const int k = 16 * wv + j;
        const uint2 u2 = ((const uint2*)(LcB + (size_t)k * N_))[ln];
        float a = blo(u2.x) * w4.x + bhi(u2.x) * w4.y + blo(u2.y) * w4.z + bhi(u2.y) * w4.w;
        a = wred_f(a);
        if (ln == j) vk = a;
      }
      if (ln < 16) v_s[16 * wv + ln] = vk;
    }
    __syncthreads();  // B1

    // ---- Phase S1: stage-1 partials for my 500 scenarios (4 n-quarters x 250 pairs) ----
    const float cc = c_sh;
    {
      const int q = t >> 8;     // n-quarter (64 n)
      const int idx = t & 255;  // scenario-pair
      if (idx < SCH_ / 2) {
        const uint32_t* col = (const uint32_t*)(epsTB + (size_t)(64 * q) * S_) + (s0 / 2 + idx);
        float a0 = 0.0f, a1 = 0.0f;
#pragma unroll 8
        for (int j = 0; j < 64; ++j) {
          const uint32_t u = col[(size_t)j * (S_ / 2)];
          const float vv = v_s[64 * q + j];
          a0 = fmaf(blo(u), vv, a0);
          a1 = fmaf(bhi(u), vv, a1);
        }
        *(float2*)&sc1[q * SCH_ + 2 * idx] = make_float2(a0, a1);
      }
    }
    __syncthreads();  // B2

    // ---- Phase P: combine + publish keys + own-key pass-0 histogram ----
    unsigned* lgbuf = lossbits + ((it & 1) ? (size_t)B_ * S_ : 0) + (size_t)b * S_;
    if (t < SCH_) {
      const float lv = -(cc + ((sc1[t] + sc1[SCH_ + t]) + (sc1[2 * SCH_ + t] + sc1[3 * SCH_ + t])));
      const unsigned kd = keyd(lv);
      __hip_atomic_store(&lgbuf[s0 + t], kd, __ATOMIC_RELAXED, __HIP_MEMORY_SCOPE_AGENT);
      atomicAdd(&hist[0][kd >> 24], 1);
    }
    __syncthreads();  // B3 (drains vmcnt before bar-add)

    // ---- Phase W: per-batch spin barrier ----
    if (t == 0) {
      __hip_atomic_fetch_add(&bar[b], 1, __ATOMIC_RELAXED, __HIP_MEMORY_SCOPE_AGENT);
      const int target = PART_ * (it + 1);
      while (__hip_atomic_load(&bar[b], __ATOMIC_RELAXED, __HIP_MEMORY_SCOPE_AGENT) < target) {
        __builtin_amdgcn_s_sleep(1);
      }
    }
    __syncthreads();  // B4

    // ---- Phase G: gather all 2000 keys (uint64) + remote-key pass-0 histogram ----
    uint32_t kx = 0xFFFFFFFFu, ky = 0xFFFFFFFFu;
    if (t < S_ / 2) {
      const unsigned long long two = __hip_atomic_load(
          (const unsigned long long*)(lgbuf + 2 * t), __ATOMIC_RELAXED, __HIP_MEMORY_SCOPE_AGENT);
      kx = (uint32_t)two;
      ky = (uint32_t)(two >> 32);
      if ((unsigned)(2 * t - s0) >= (unsigned)SCH_) {  // pair entirely remote (SCH_ even)
        atomicAdd(&hist[0][kx >> 24], 1);
        atomicAdd(&hist[0][ky >> 24], 1);
      }
    }
    __syncthreads();  // B5

    // ---- 4-pass radix select: redundant all-wave scan; compact at last pass ----
    unsigned pref = 0;
    int r = K_;
#pragma unroll
    for (int pass = 0; pass < 4; ++pass) {
      const int shift = 24 - 8 * pass;
      {
        const int4 c4 = *(const int4*)&hist[pass][4 * ln];
        const int c0 = c4.x, c1 = c4.y, c2 = c4.z, c3 = c4.w;
        const int tot = c0 + c1 + c2 + c3;
        int sc = tot;
#pragma unroll
        for (int off = 1; off < 64; off <<= 1) {
          const int o = __shfl_up(sc, off);
          if (ln >= off) sc += o;
        }
        const int excl = sc - tot;
        const bool has = (excl < r) && (r <= sc);
        const unsigned long long bal = __ballot(has);
        const int lstar = __ffsll(bal) - 1;
        const int bc0 = __shfl(c0, lstar);
        const int bc1 = __shfl(c1, lstar);
        const int bc2 = __shfl(c2, lstar);
        const int bexcl = __shfl(excl, lstar);
        const int rr = r - bexcl;
        int d, rn;
        if (rr <= bc0) { d = 0; rn = rr; }
        else if (rr <= bc0 + bc1) { d = 1; rn = rr - bc0; }
        else if (rr <= bc0 + bc1 + bc2) { d = 2; rn = rr - bc0 - bc1; }
        else { d = 3; rn = rr - bc0 - bc1 - bc2; }
        pref |= (unsigned)(4 * lstar + d) << shift;
        r = rn;
      }
      if (pass < 3) {
        const unsigned msk = 0xFFFFFFFFu << shift;
        const int nshift = shift - 8;
        if (t < S_ / 2) {
          if ((kx & msk) == pref) atomicAdd(&hist[pass + 1][(kx >> nshift) & 255], 1);
          if ((ky & msk) == pref) atomicAdd(&hist[pass + 1][(ky >> nshift) & 255], 1);
        }
      } else {
        if (t < S_ / 2) {
          if (kx <= pref) { const int p = atomicAdd(&lcnt, 1); lists[p] = (uint16_t)(2 * t); }
          if (ky <= pref) { const int p = atomicAdd(&lcnt, 1); lists[p] = (uint16_t)(2 * t + 1); }
        }
      }
      __syncthreads();  // B6..B9
    }

    const int cnt = lcnt;
    const float weight = 1.0f / (float)((cnt > K_) ? cnt : K_);

    // ---- Phase E: e partials (8 row-groups x 128 n-pairs, dual-accumulator ILP) ----
    {
      const int rt = t >> 7;
      const int np = t & 127;
      float a0 = 0.0f, a1 = 0.0f, b0 = 0.0f, b1 = 0.0f;
      for (int p = rt; p < cnt; p += 16) {
        const uint32_t u = *((const uint32_t*)(epsRB + (size_t)lists[p] * N_) + np);
        a0 += blo(u);
        a1 += bhi(u);
        const int p2 = p + 8;
        if (p2 < cnt) {
          const uint32_t u2 = *((const uint32_t*)(epsRB + (size_t)lists[p2] * N_) + np);
          b0 += blo(u2);
          b1 += bhi(u2);
        }
      }
      *(float2*)&scratch[rt][2 * np] = make_float2(a0 + b0, a1 + b1);
    }
    __syncthreads();  // B10

    // ---- Phase U: u = L e wave-cooperative with inline 8-way e-reduce ----
    {
      float4 e4 = make_float4(0.0f, 0.0f, 0.0f, 0.0f);
#pragma unroll
      for (int g = 0; g < 8; ++g) {
        const float4 x = *(const float4*)&scratch[g][4 * ln];
        e4.x += x.x; e4.y += x.y; e4.z += x.z; e4.w += x.w;
      }
      float ui = 0.0f;
#pragma unroll
      for (int j = 0; j < 16; ++j) {
        const int i = 16 * wv + j;
        const uint2 u2 = ((const uint2*)(LrB + (size_t)i * N_))[ln];
        float a = blo(u2.x) * e4.x + bhi(u2.x) * e4.y + blo(u2.y) * e4.z + bhi(u2.y) * e4.w;
        a = wred_f(a);
        if (ln == j) ui = a;
      }
      if (ln < 16) u_s[16 * wv + ln] = ui;
    }
    __syncthreads();  // B11

    // ---- Phase PR: w <- proj(w + lr*(mu_eff + u*weight)), warm Michelot (wave 0) ----
    if (t < 64) {
      const float th0 = th_sh;
      const float lr = 0.5f / sqrtf((float)it + 1.0f);
      const float4 w4 = *(const float4*)(w_s + 4 * ln);
      const float4 u4 = *(const float4*)(u_s + 4 * ln);
      const float4 m4 = *(const float4*)(muB + 4 * ln);
      float y[4];
      y[0] = w4.x + lr * (muf * m4.x + u4.x * weight);
      y[1] = w4.y + lr * (muf * m4.y + u4.y * weight);
      y[2] = w4.z + lr * (muf * m4.z + u4.z * weight);
      y[3] = w4.w + lr * (muf * m4.w + u4.w * weight);
      proj_store(y, fl_bil, mass, muf, muB, ln, th0, w_s, &c_sh, &th_sh);
    }
    __syncthreads();  // B12 (doubles as next iteration's B0)
  }

  // ---- output (part 0 only): w / (sum + 1e-8) ----
  if (part == 0) {
    if (t < 64) {
      const float4 w4 = *(const float4*)(w_s + 4 * ln);
      const float ssum = wred_f(w4.x + w4.y + w4.z + w4.w);
      if (ln == 0) sum_sh = ssum;
    }
    __syncthreads();
    if (t < N_) out[(size_t)b * N_ + t] = fmaxf(w_s[t], 0.0f) / (sum_sh + 1e-8f);
  }
}

extern "C" void kernel_launch(void* const* d_in, const int* in_sizes, int n_in,
                              void* d_out, int out_size, void* d_ws, size_t ws_size,
                              hipStream_t stream) {
  const float* mu = (const float*)d_in[0];
  const float* sigma = (const float*)d_in[1];
  const float* eps = (const float*)d_in[2];
  const int* crisis = (const int*)d_in[3];
  const int* lam = (const int*)d_in[4];
  float* out = (float*)d_out;
  float* ws = (float*)d_ws;

  uint16_t* Lc16 = (uint16_t*)(ws + OFF_LC16);
  uint16_t* Lr16 = (uint16_t*)(ws + OFF_LR16);
  uint16_t* epsT16 = (uint16_t*)(ws + OFF_EPST);
  uint16_t* epsrm16 = (uint16_t*)(ws + OFF_EPSRM);
  float* Lc = ws + OFF_EPSRM;  // fp32 L aliases epsrm16 (dead before etrans writes it)
  unsigned* lossbits = (unsigned*)(ws + OFF_LOSS);
  int* bar = (int*)(ws + OFF_BAR);

  chol_kernel<<<dim3(B_), dim3(512), 0, stream>>>(sigma, Lc);
  lpack_kernel<<<dim3(B_), dim3(256), 0, stream>>>(Lc, Lc16, Lr16);
  etrans_kernel<<<dim3(B_, S_ / 50), dim3(256), 0, stream>>>(eps, epsT16, epsrm16, bar);

  solve_kernel<<<dim3(PART_ * B_), dim3(1024), 0, stream>>>(
      mu, crisis, lam, Lc16, Lr16, epsT16, epsrm16, lossbits, bar, out);
}

// Round 9
// 4253.532 us; speedup vs baseline: 2.1151x; 2.1151x over previous
//
#include <hip/hip_runtime.h>
#include <stdint.h>

#define B_   64
#define N_   256
#define S_   2000
#define K_   100
#define BIL_ 4
#define NITER_ 200
#define JITTER_ 1e-4f
#define SAFETY_ 0.5f
#define PART_ 4
#define SCH_  (S_ / PART_)   // 500 scenarios per block

// ---- ws layout (offsets in float units) ----
#define OFF_LC16  ((size_t)0)                                   // bf16 L col-major
#define OFF_LR16  (OFF_LC16 + (size_t)B_ * N_ * N_ / 2)         // bf16 L row-major
#define OFF_EPST  (OFF_LR16 + (size_t)B_ * N_ * N_ / 2)         // bf16 epsT[b][n][s]
#define OFF_EPSRM (OFF_EPST + (size_t)B_ * N_ * S_ / 2)         // bf16 eps[b][s][n] (& temp fp32 Lc)
#define OFF_LOSS  (OFF_EPSRM + (size_t)B_ * S_ * N_ / 2)        // uint loss keys, double-buffered
#define OFF_BAR   (OFF_LOSS + (size_t)2 * B_ * S_)              // int barrier counters

// ---------------- helpers ----------------
__device__ __forceinline__ float wred_f(float x) {
#pragma unroll
  for (int off = 32; off > 0; off >>= 1) x += __shfl_xor(x, off);
  return x;
}
// monotone key: larger loss -> SMALLER key (top-K largest = K smallest keys)
__device__ __forceinline__ unsigned keyd(float x) {
  unsigned u = __float_as_uint(x);
  unsigned ku = (u & 0x80000000u) ? ~u : (u | 0x80000000u);
  return ~ku;
}
__device__ __forceinline__ uint16_t f2b(float f) {  // RNE fp32->bf16
  uint32_t u = __float_as_uint(f);
  uint32_t r = u + 0x7FFFu + ((u >> 16) & 1u);
  return (uint16_t)(r >> 16);
}
__device__ __forceinline__ float blo(uint32_t u) { return __uint_as_float(u << 16); }
__device__ __forceinline__ float bhi(uint32_t u) { return __uint_as_float(u & 0xFFFF0000u); }

// Fixed-point simplex projection (same fixed point as reference's sort formula).
// Warm-started from theta0 (r8-validated); active count via ballots (SALU-side).
__device__ __forceinline__ float michelot4(const float vp[4], float z, float theta0) {
  float theta = theta0;
  int prev = -1;
  for (int pass = 0; pass < 300; ++pass) {
    const bool a0 = vp[0] > theta, a1 = vp[1] > theta, a2 = vp[2] > theta, a3 = vp[3] > theta;
    float ls = 0.0f;
    if (a0) ls += vp[0];
    if (a1) ls += vp[1];
    if (a2) ls += vp[2];
    if (a3) ls += vp[3];
    const int lc = __popcll(__ballot(a0)) + __popcll(__ballot(a1)) +
                   __popcll(__ballot(a2)) + __popcll(__ballot(a3));
    ls = wred_f(ls);
    if (lc == 0) {  // over-warm start excluded everything: cold restart
      theta = -1e30f;
      prev = -1;
      continue;
    }
    theta = (ls - z) / (float)lc;
    if (lc == prev) break;
    prev = lc;
  }
  return theta;
}

__device__ __forceinline__ void proj_store(const float y[4], float fl_bil, float mass, float muf,
                                           const float* __restrict__ muB, int ln, float theta0,
                                           float* w_s, float* c_sh, float* th_sh) {
  float vp[4];
#pragma unroll
  for (int j = 0; j < 4; ++j) {
    const int n = 4 * ln + j;
    vp[j] = y[j] - ((n == BIL_) ? fl_bil : 0.0f);
  }
  const float theta = michelot4(vp, mass, theta0);
  const float4 m4 = *(const float4*)(muB + 4 * ln);
  const float mm[4] = {m4.x, m4.y, m4.z, m4.w};
  float wj[4];
  float cp = 0.0f;
#pragma unroll
  for (int j = 0; j < 4; ++j) {
    const int n = 4 * ln + j;
    wj[j] = fmaxf(vp[j] - theta, 0.0f) + ((n == BIL_) ? fl_bil : 0.0f);
    cp = fmaf(muf * mm[j], wj[j], cp);
  }
  cp = wred_f(cp);
  if (ln == 0) {
    *c_sh = cp;
    *th_sh = theta;
  }
  *(float4*)(w_s + 4 * ln) = make_float4(wj[0], wj[1], wj[2], wj[3]);
}

// ---------------- Cholesky v3: one block (512 thr) per batch (proven r3) ----------------
__global__ __launch_bounds__(512) void chol_kernel(const float* __restrict__ sigma,
                                                   float* __restrict__ Lc) {
  const int b = blockIdx.x;
  const int tid = threadIdx.x;
  const int i = tid & 255;
  const int half = tid >> 8;
  const float* Sg = sigma + (size_t)b * N_ * N_;
  float* L = Lc + (size_t)b * N_ * N_;
  __shared__ __align__(16) float slab[248 * 8];
  __shared__ __align__(16) float spart[256][8];
  __shared__ __align__(16) float pnl[64];

  for (int j0 = 0; j0 < N_; j0 += 8) {
    for (int x = tid; x < j0 * 8; x += 512) {
      const int k = x >> 3, jj = x & 7;
      slab[x] = L[(size_t)k * N_ + (j0 + jj)];
    }
    float s[8];
    if (half == 0) {
#pragma unroll
      for (int jj = 0; jj < 8; ++jj) {
        float a = Sg[(size_t)(j0 + jj) * N_ + i];
        if (i == j0 + jj) a += JITTER_;
        s[jj] = a;
      }
    } else {
#pragma unroll
      for (int jj = 0; jj < 8; ++jj) s[jj] = 0.0f;
    }
    __syncthreads();

    const int kb = half ? (j0 >> 1) : 0;
    const int ke = half ? j0 : (j0 >> 1);
#pragma unroll 4
    for (int k = kb; k < ke; ++k) {
      const float lk = L[(size_t)k * N_ + i];
      const float4 h0 = *(const float4*)&slab[k * 8];
      const float4 h1 = *(const float4*)&slab[k * 8 + 4];
      s[0] = fmaf(-lk, h0.x, s[0]);
      s[1] = fmaf(-lk, h0.y, s[1]);
      s[2] = fmaf(-lk, h0.z, s[2]);
      s[3] = fmaf(-lk, h0.w, s[3]);
      s[4] = fmaf(-lk, h1.x, s[4]);
      s[5] = fmaf(-lk, h1.y, s[5]);
      s[6] = fmaf(-lk, h1.z, s[6]);
      s[7] = fmaf(-lk, h1.w, s[7]);
    }
    if (half == 1) {
      *(float4*)&spart[i][0] = make_float4(s[0], s[1], s[2], s[3]);
      *(float4*)&spart[i][4] = make_float4(s[4], s[5], s[6], s[7]);
    }
    __syncthreads();

    if (half == 0) {
      const float4 p0 = *(const float4*)&spart[i][0];
      const float4 p1 = *(const float4*)&spart[i][4];
      s[0] += p0.x; s[1] += p0.y; s[2] += p0.z; s[3] += p0.w;
      s[4] += p1.x; s[5] += p1.y; s[6] += p1.z; s[7] += p1.w;
      if ((i >> 3) == (j0 >> 3)) {
        const int base = j0 & 63;
        const int r = i & 7;
        float l[8], di[8];
#pragma unroll
        for (int m = 0; m < 8; ++m) {
          const float smv = __shfl(s[m], base + m);
          const float d = sqrtf(smv);
          const float dinv = 1.0f / d;
          di[m] = dinv;
          float lm;
          if (r == m) lm = d;
          else if (r > m) lm = s[m] * dinv;
          else lm = 0.0f;
          l[m] = lm;
#pragma unroll
          for (int mm = m + 1; mm < 8; ++mm) {
            s[mm] = fmaf(-lm, __shfl(lm, base + mm), s[mm]);
          }
        }
#pragma unroll
        for (int m = 0; m < 8; ++m) pnl[r * 8 + m] = (m < r) ? l[m] : ((m == r) ? di[r] : 0.0f);
#pragma unroll
        for (int m = 0; m < 8; ++m) L[(size_t)(j0 + m) * N_ + i] = l[m];
      }
    }
    __syncthreads();

    if (half == 0 && (i >> 3) != (j0 >> 3)) {
      float l[8];
      if (i > j0) {
#pragma unroll
        for (int m = 0; m < 8; ++m) {
          float sm = s[m];
#pragma unroll
          for (int mm = 0; mm < 8; ++mm) {
            if (mm < m) sm = fmaf(-l[mm], pnl[m * 8 + mm], sm);
          }
          l[m] = sm * pnl[m * 8 + m];
        }
      } else {
#pragma unroll
        for (int m = 0; m < 8; ++m) l[m] = 0.0f;
      }
#pragma unroll
      for (int m = 0; m < 8; ++m) L[(size_t)(j0 + m) * N_ + i] = l[m];
    }
    __syncthreads();
  }
}

// ---------------- pack L ----------------
__global__ __launch_bounds__(256) void lpack_kernel(const float* __restrict__ Lc,
                                                    uint16_t* __restrict__ Lc16,
                                                    uint16_t* __restrict__ Lr16) {
  const int b = blockIdx.x;
  const float* Lp = Lc + (size_t)b * N_ * N_;
  uint16_t* C16 = Lc16 + (size_t)b * N_ * N_;
  uint16_t* R16 = Lr16 + (size_t)b * N_ * N_;
  __shared__ float tl[32][33];
  const int tx = threadIdx.x & 31;
  const int ty = threadIdx.x >> 5;
  for (int kt = 0; kt < 8; ++kt) {
    for (int it = 0; it < 8; ++it) {
#pragma unroll
      for (int rr = 0; rr < 4; ++rr) {
        const int k = kt * 32 + ty + 8 * rr;
        const int ii = it * 32 + tx;
        const float v = Lp[(size_t)k * N_ + ii];
        tl[ty + 8 * rr][tx] = v;
        C16[(size_t)k * N_ + ii] = f2b(v);
      }
      __syncthreads();
#pragma unroll
      for (int rr = 0; rr < 4; ++rr) {
        const int ii = it * 32 + ty + 8 * rr;
        const int k = kt * 32 + tx;
        R16[(size_t)ii * N_ + k] = f2b(tl[tx][ty + 8 * rr]);
      }
      __syncthreads();
    }
  }
}

// ---------------- eps -> bf16 both layouts; zero bar ----------------
__global__ __launch_bounds__(256) void etrans_kernel(const float* __restrict__ eps,
                                                     uint16_t* __restrict__ epsT16,
                                                     uint16_t* __restrict__ epsrm16,
                                                     int* __restrict__ bar) {
  const int b = blockIdx.x;
  const int s0 = blockIdx.y * 50;
  const int t = threadIdx.x;
  if (blockIdx.x == 0 && blockIdx.y == 0 && t < 64) bar[t] = 0;
  __shared__ float tl[50][257];
  const float* E = eps + ((size_t)b * S_ + s0) * N_;
  for (int p = 0; p < 50; ++p) tl[p][t] = E[(size_t)p * N_ + t];
  __syncthreads();
  uint16_t* RM = epsrm16 + ((size_t)b * S_ + s0) * N_;
  for (int p = 0; p < 50; ++p) RM[(size_t)p * N_ + t] = f2b(tl[p][t]);
  uint16_t* ET = epsT16 + (size_t)b * N_ * S_;
  const int g = t / 50, ss = t % 50;
  if (g < 5) {
    for (int q = 0; q < 52; ++q) {
      const int n = q * 5 + g;
      if (n < N_) ET[(size_t)n * S_ + s0 + ss] = f2b(tl[ss][n]);
    }
  }
}

// ---------------- solver: 4 blocks (1024 thr) per batch, grid 256, plain launch ----------------
// r9 = r7 structure (proven) + warm ballot-Michelot + pre-spin own-key hist + e-ILP.
// NOTE (r8 lesson): partial-write -> barrier -> reduce matvecs beat wave-shuffle
// matvecs here (r8's shuffle version: FETCH +70%, dur 2.2x).
__global__ __launch_bounds__(1024) void solve_kernel(
    const float* __restrict__ mu, const int* __restrict__ pcrisis,
    const int* __restrict__ plam, const uint16_t* __restrict__ Lc16,
    const uint16_t* __restrict__ Lr16, const uint16_t* __restrict__ epsT16,
    const uint16_t* __restrict__ epsrm16, unsigned* __restrict__ lossbits,
    int* __restrict__ bar, float* __restrict__ out) {
  const int bx = blockIdx.x;
  const int b = bx & (B_ - 1);
  const int part = bx >> 6;  // 0..3; blocks b+64k land on XCD b%8 under %8 RR
  const int t = threadIdx.x;
  const int ln = t & 63;
  const int s0 = part * SCH_;

  __shared__ __align__(16) float w_s[N_];
  __shared__ __align__(16) float v_s[N_];
  __shared__ __align__(16) float scratch[8][N_];  // matvec/stage1/e partials (flat-aliased)
  __shared__ __align__(16) uint16_t lists[S_];
  __shared__ __align__(16) int hist[4][256];      // one bank per radix pass
  __shared__ float c_sh;
  __shared__ float th_sh;
  __shared__ int lcnt;
  __shared__ float sum_sh;

  const int crisis = pcrisis[0];
  const int lamv = plam[0];
  const float muf = 1.0f + ((lamv > 0) ? (1.0f / fmaxf((float)lamv, 0.1f)) : 0.0f);
  const float fl_bil = SAFETY_ * (float)crisis;
  const float mass = 1.0f - fl_bil;

  const uint16_t* LcB = Lc16 + (size_t)b * N_ * N_;
  const uint16_t* LrB = Lr16 + (size_t)b * N_ * N_;
  const float* muB = mu + (size_t)b * N_;
  const uint16_t* epsTB = epsT16 + (size_t)b * N_ * S_;
  const uint16_t* epsRB = epsrm16 + (size_t)b * S_ * N_;
  float* sc1 = &scratch[0][0];

  // ---- w0 = proj(uniform), cold-start theta ----
  if (t < 64) {
    float y[4];
#pragma unroll
    for (int j = 0; j < 4; ++j) y[j] = 1.0f / (float)N_;
    proj_store(y, fl_bil, mass, muf, muB, ln, -1e30f, w_s, &c_sh, &th_sh);
  }
  __syncthreads();  // B1

  for (int it = 0; it < NITER_; ++it) {
    // ---- v = L^T w partials: 8 i-octants x 128 k-pairs ----
    {
      const int oct = t >> 7, kp = t & 127;
      const uint32_t* Lp = (const uint32_t*)(LrB) + kp;
      const int i0 = 32 * oct;
      float a0 = 0.0f, a1 = 0.0f;
#pragma unroll 8
      for (int ii = 0; ii < 32; ++ii) {
        const uint32_t u = Lp[(size_t)(i0 + ii) * (N_ / 2)];
        const float ww = w_s[i0 + ii];
        a0 = fmaf(blo(u), ww, a0);
        a1 = fmaf(bhi(u), ww, a1);
      }
      *(float2*)&scratch[oct][2 * kp] = make_float2(a0, a1);
    }
    __syncthreads();  // B2

    // ---- v-reduce (t<256) + zero hist banks & lcnt (t>=256) ----
    if (t < N_) {
      v_s[t] = ((scratch[0][t] + scratch[1][t]) + (scratch[2][t] + scratch[3][t])) +
               ((scratch[4][t] + scratch[5][t]) + (scratch[6][t] + scratch[7][t]));
    } else {
      for (int x = t - 256; x < 4 * 256; x += 768) ((int*)hist)[x] = 0;
      if (t == 256) lcnt = 0;
    }
    __syncthreads();  // B3

    // ---- stage 1: partial losses for my 500 scenarios (4 n-quarters x 250 pairs) ----
    const float cc = c_sh;
    {
      const int q = t >> 8;     // n-quarter (64 n)
      const int idx = t & 255;  // scenario-pair
      if (idx < SCH_ / 2) {
        const uint32_t* col = (const uint32_t*)(epsTB + (size_t)(64 * q) * S_) + (s0 / 2 + idx);
        float a0 = 0.0f, a1 = 0.0f;
#pragma unroll 8
        for (int j = 0; j < 64; ++j) {
          const uint32_t u = col[(size_t)j * (S_ / 2)];
          const float vv = v_s[64 * q + j];
          a0 = fmaf(blo(u), vv, a0);
          a1 = fmaf(bhi(u), vv, a1);
        }
        *(float2*)&sc1[q * SCH_ + 2 * idx] = make_float2(a0, a1);
      }
    }
    __syncthreads();  // B4

    // ---- combine + publish keys + own-key pass-0 histogram (overlaps the spin) ----
    unsigned* lgbuf = lossbits + ((it & 1) ? (size_t)B_ * S_ : 0) + (size_t)b * S_;
    if (t < SCH_) {
      const float lv = -(cc + ((sc1[t] + sc1[SCH_ + t]) + (sc1[2 * SCH_ + t] + sc1[3 * SCH_ + t])));
      const unsigned kd = keyd(lv);
      __hip_atomic_store(&lgbuf[s0 + t], kd, __ATOMIC_RELAXED, __HIP_MEMORY_SCOPE_AGENT);
      atomicAdd(&hist[0][kd >> 24], 1);
    }
    __syncthreads();  // B5 (drains vmcnt before barrier entry)

    // ---- per-batch spin barrier ----
    if (t == 0) {
      __hip_atomic_fetch_add(&bar[b], 1, __ATOMIC_RELAXED, __HIP_MEMORY_SCOPE_AGENT);
      const int target = PART_ * (it + 1);
      while (__hip_atomic_load(&bar[b], __ATOMIC_RELAXED, __HIP_MEMORY_SCOPE_AGENT) < target) {
        __builtin_amdgcn_s_sleep(1);
      }
    }
    __syncthreads();  // B6

    // ---- gather all 2000 keys into registers; histogram only REMOTE pairs ----
    uint32_t kx = 0xFFFFFFFFu, ky = 0xFFFFFFFFu;
    if (t < S_ / 2) {
      const unsigned long long two = __hip_atomic_load(
          (const unsigned long long*)(lgbuf + 2 * t), __ATOMIC_RELAXED, __HIP_MEMORY_SCOPE_AGENT);
      kx = (uint32_t)two;
      ky = (uint32_t)(two >> 32);
      if ((unsigned)(2 * t - s0) >= (unsigned)SCH_) {  // pair entirely remote (SCH_ even)
        atomicAdd(&hist[0][kx >> 24], 1);
        atomicAdd(&hist[0][ky >> 24], 1);
      }
    }
    __syncthreads();  // B7

    // ---- 4-pass radix select: redundant all-wave scan (no publish barrier) ----
    unsigned pref = 0;
    int r = K_;
#pragma unroll
    for (int pass = 0; pass < 4; ++pass) {
      const int shift = 24 - 8 * pass;
      {
        const int4 c4 = *(const int4*)&hist[pass][4 * ln];
        const int c0 = c4.x, c1 = c4.y, c2 = c4.z, c3 = c4.w;
        const int tot = c0 + c1 + c2 + c3;
        int sc = tot;
#pragma unroll
        for (int off = 1; off < 64; off <<= 1) {
          const int o = __shfl_up(sc, off);
          if (ln >= off) sc += o;
        }
        const int excl = sc - tot;
        const bool has = (excl < r) && (r <= sc);
        const unsigned long long bal = __ballot(has);
        const int lstar = __ffsll(bal) - 1;
        const int bc0 = __shfl(c0, lstar);
        const int bc1 = __shfl(c1, lstar);
        const int bc2 = __shfl(c2, lstar);
        const int bexcl = __shfl(excl, lstar);
        const int rr = r - bexcl;
        int d, rn;
        if (rr <= bc0) { d = 0; rn = rr; }
        else if (rr <= bc0 + bc1) { d = 1; rn = rr - bc0; }
        else if (rr <= bc0 + bc1 + bc2) { d = 2; rn = rr - bc0 - bc1; }
        else { d = 3; rn = rr - bc0 - bc1 - bc2; }
        pref |= (unsigned)(4 * lstar + d) << shift;
        r = rn;
      }
      if (pass < 3) {
        const unsigned msk = 0xFFFFFFFFu << shift;
        const int nshift = shift - 8;
        if (t < S_ / 2) {
          if ((kx & msk) == pref) atomicAdd(&hist[pass + 1][(kx >> nshift) & 255], 1);
          if ((ky & msk) == pref) atomicAdd(&hist[pass + 1][(ky >> nshift) & 255], 1);
        }
      } else {
        if (t < S_ / 2) {
          if (kx <= pref) { const int p = atomicAdd(&lcnt, 1); lists[p] = (uint16_t)(2 * t); }
          if (ky <= pref) { const int p = atomicAdd(&lcnt, 1); lists[p] = (uint16_t)(2 * t + 1); }
        }
      }
      __syncthreads();  // B8..B11
    }

    const int cnt = lcnt;
    const float weight = 1.0f / (float)((cnt > K_) ? cnt : K_);

    // ---- e partials: 8 row-groups x 128 n-pairs, dual-accumulator ILP ----
    {
      const int rt = t >> 7;
      const int np = t & 127;
      float a0 = 0.0f, a1 = 0.0f, b0 = 0.0f, b1 = 0.0f;
      for (int p = rt; p < cnt; p += 16) {
        const uint32_t u = *((const uint32_t*)(epsRB + (size_t)lists[p] * N_) + np);
        a0 += blo(u);
        a1 += bhi(u);
        const int p2 = p + 8;
        if (p2 < cnt) {
          const uint32_t u2 = *((const uint32_t*)(epsRB + (size_t)lists[p2] * N_) + np);
          b0 += blo(u2);
          b1 += bhi(u2);
        }
      }
      *(float2*)&scratch[rt][2 * np] = make_float2(a0 + b0, a1 + b1);
    }
    __syncthreads();  // B12

    // ---- e-reduce (wave 0) into v_s ----
    if (t < 64) {
      float4 acc = make_float4(0.0f, 0.0f, 0.0f, 0.0f);
#pragma unroll
      for (int oct = 0; oct < 8; ++oct) {
        const float4 x = *(const float4*)&scratch[oct][4 * ln];
        acc.x += x.x; acc.y += x.y; acc.z += x.z; acc.w += x.w;
      }
      *(float4*)&v_s[4 * ln] = acc;
    }
    __syncthreads();  // B12b: e ready in v_s

    // ---- u = L e partials: 8 k-octants x 128 i-pairs ----
    {
      const int oct = t >> 7, ip = t & 127;
      const uint32_t* Lp = (const uint32_t*)(LcB) + ip;
      const int k0 = 32 * oct;
      float a0 = 0.0f, a1 = 0.0f;
#pragma unroll 8
      for (int kk = 0; kk < 32; ++kk) {
        const uint32_t u = Lp[(size_t)(k0 + kk) * (N_ / 2)];
        const float ee = v_s[k0 + kk];
        a0 = fmaf(blo(u), ee, a0);
        a1 = fmaf(bhi(u), ee, a1);
      }
      *(float2*)&scratch[oct][2 * ip] = make_float2(a0, a1);
    }
    __syncthreads();  // B13

    // ---- w update + projection (wave 0), u-reduce fused, warm-start Michelot ----
    if (t < 64) {
      const float th0 = th_sh;
      float4 u4 = make_float4(0.0f, 0.0f, 0.0f, 0.0f);
#pragma unroll
      for (int oct = 0; oct < 8; ++oct) {
        const float4 x = *(const float4*)&scratch[oct][4 * ln];
        u4.x += x.x; u4.y += x.y; u4.z += x.z; u4.w += x.w;
      }
      const float lr = 0.5f / sqrtf((float)it + 1.0f);
      const float4 w4 = *(const float4*)(w_s + 4 * ln);
      const float4 m4 = *(const float4*)(muB + 4 * ln);
      float y[4];
      y[0] = w4.x + lr * (muf * m4.x + u4.x * weight);
      y[1] = w4.y + lr * (muf * m4.y + u4.y * weight);
      y[2] = w4.z + lr * (muf * m4.z + u4.z * weight);
      y[3] = w4.w + lr * (muf * m4.w + u4.w * weight);
      proj_store(y, fl_bil, mass, muf, muB, ln, th0, w_s, &c_sh, &th_sh);
    }
    __syncthreads();  // B14 (doubles as next iteration's B1)
  }

  // ---- output (part 0 only): w / (sum + 1e-8) ----
  if (part == 0) {
    if (t < 64) {
      const float4 w4 = *(const float4*)(w_s + 4 * ln);
      const float ssum = wred_f(w4.x + w4.y + w4.z + w4.w);
      if (ln == 0) sum_sh = ssum;
    }
    __syncthreads();
    if (t < N_) out[(size_t)b * N_ + t] = fmaxf(w_s[t], 0.0f) / (sum_sh + 1e-8f);
  }
}

extern "C" void kernel_launch(void* const* d_in, const int* in_sizes, int n_in,
                              void* d_out, int out_size, void* d_ws, size_t ws_size,
                              hipStream_t stream) {
  const float* mu = (const float*)d_in[0];
  const float* sigma = (const float*)d_in[1];
  const float* eps = (const float*)d_in[2];
  const int* crisis = (const int*)d_in[3];
  const int* lam = (const int*)d_in[4];
  float* out = (float*)d_out;
  float* ws = (float*)d_ws;

  uint16_t* Lc16 = (uint16_t*)(ws + OFF_LC16);
  uint16_t* Lr16 = (uint16_t*)(ws + OFF_LR16);
  uint16_t* epsT16 = (uint16_t*)(ws + OFF_EPST);
  uint16_t* epsrm16 = (uint16_t*)(ws + OFF_EPSRM);
  float* Lc = ws + OFF_EPSRM;  // fp32 L aliases epsrm16 (dead before etrans writes it)
  unsigned* lossbits = (unsigned*)(ws + OFF_LOSS);
  int* bar = (int*)(ws + OFF_BAR);

  chol_kernel<<<dim3(B_), dim3(512), 0, stream>>>(sigma, Lc);
  lpack_kernel<<<dim3(B_), dim3(256), 0, stream>>>(Lc, Lc16, Lr16);
  etrans_kernel<<<dim3(B_, S_ / 50), dim3(256), 0, stream>>>(eps, epsT16, epsrm16, bar);

  solve_kernel<<<dim3(PART_ * B_), dim3(1024), 0, stream>>>(
      mu, crisis, lam, Lc16, Lr16, epsT16, epsrm16, lossbits, bar, out);
}